// Round 1
// baseline (471.506 us; speedup 1.0000x reference)
//
#include <hip/hip_runtime.h>
#include <math.h>

#define N_TOK  16384
#define DIM    4096
#define NE     64
#define CAP    640
#define KC     32
#define TM     128
#define NTILES (N_TOK / TM)   // 128

// ws layout:
// [0,256):                     counts (64 int, zeroed per call)
// [256, 256+128K):             ws_idx   (int,   N*2)
// [256+128K, 256+256K):        ws_probs (float, N*2)
// [262400, ...):               partials (ks * N * 64 floats)

__global__ __launch_bounds__(256) void gemm_logits_kernel(
    const float* __restrict__ x, const float* __restrict__ W,
    float* __restrict__ partials, int ks) {
  const int tile  = blockIdx.x % NTILES;
  const int split = blockIdx.x / NTILES;
  const int klen  = DIM / ks;
  const int k0    = split * klen;
  const int t_base = tile * TM;

  // double-buffered tiles; padded strides keep inner-loop reads ~conflict-free
  __shared__ float xT[2][KC][TM + 4];  // 2 x 16.9 KB
  __shared__ float wT[2][KC][NE + 4];  // 2 x  8.7 KB   (total 51.2 KB)

  const int tid = threadIdx.x;
  const int lr = tid >> 3;   // 0..31
  const int lc = tid & 7;    // 0..7
  const int tg = tid >> 3;   // token group: tokens tg*4 .. tg*4+3
  const int eg = tid & 7;    // expert group: experts eg*8 .. eg*8+7

  float acc[4][8];
#pragma unroll
  for (int i = 0; i < 4; ++i)
#pragma unroll
    for (int j = 0; j < 8; ++j) acc[i][j] = 0.f;

  // register staging buffers (in-flight tile)
  float4 rx0, rx1, rx2, rx3, rw0, rw1;

  // ---- prologue: load tile 0 into regs, write LDS buf 0 ----
  {
    const int kg = k0;
    rx0 = *(const float4*)(x + (size_t)(t_base + lr +  0) * DIM + kg + lc * 4);
    rx1 = *(const float4*)(x + (size_t)(t_base + lr + 32) * DIM + kg + lc * 4);
    rx2 = *(const float4*)(x + (size_t)(t_base + lr + 64) * DIM + kg + lc * 4);
    rx3 = *(const float4*)(x + (size_t)(t_base + lr + 96) * DIM + kg + lc * 4);
    rw0 = *(const float4*)(W + (size_t)(lr +  0) * DIM + kg + lc * 4);
    rw1 = *(const float4*)(W + (size_t)(lr + 32) * DIM + kg + lc * 4);
    xT[0][lc * 4 + 0][lr +  0] = rx0.x; xT[0][lc * 4 + 1][lr +  0] = rx0.y;
    xT[0][lc * 4 + 2][lr +  0] = rx0.z; xT[0][lc * 4 + 3][lr +  0] = rx0.w;
    xT[0][lc * 4 + 0][lr + 32] = rx1.x; xT[0][lc * 4 + 1][lr + 32] = rx1.y;
    xT[0][lc * 4 + 2][lr + 32] = rx1.z; xT[0][lc * 4 + 3][lr + 32] = rx1.w;
    xT[0][lc * 4 + 0][lr + 64] = rx2.x; xT[0][lc * 4 + 1][lr + 64] = rx2.y;
    xT[0][lc * 4 + 2][lr + 64] = rx2.z; xT[0][lc * 4 + 3][lr + 64] = rx2.w;
    xT[0][lc * 4 + 0][lr + 96] = rx3.x; xT[0][lc * 4 + 1][lr + 96] = rx3.y;
    xT[0][lc * 4 + 2][lr + 96] = rx3.z; xT[0][lc * 4 + 3][lr + 96] = rx3.w;
    wT[0][lc * 4 + 0][lr +  0] = rw0.x; wT[0][lc * 4 + 1][lr +  0] = rw0.y;
    wT[0][lc * 4 + 2][lr +  0] = rw0.z; wT[0][lc * 4 + 3][lr +  0] = rw0.w;
    wT[0][lc * 4 + 0][lr + 32] = rw1.x; wT[0][lc * 4 + 1][lr + 32] = rw1.y;
    wT[0][lc * 4 + 2][lr + 32] = rw1.z; wT[0][lc * 4 + 3][lr + 32] = rw1.w;
  }

  const int niter = klen / KC;
  for (int it = 0; it < niter; ++it) {
    const int cur = it & 1;
    const int nxt = cur ^ 1;
    const bool more = (it + 1 < niter);

    // issue next tile's global loads EARLY — latency hides under the FMAs below
    if (more) {
      const int kg = k0 + (it + 1) * KC;
      rx0 = *(const float4*)(x + (size_t)(t_base + lr +  0) * DIM + kg + lc * 4);
      rx1 = *(const float4*)(x + (size_t)(t_base + lr + 32) * DIM + kg + lc * 4);
      rx2 = *(const float4*)(x + (size_t)(t_base + lr + 64) * DIM + kg + lc * 4);
      rx3 = *(const float4*)(x + (size_t)(t_base + lr + 96) * DIM + kg + lc * 4);
      rw0 = *(const float4*)(W + (size_t)(lr +  0) * DIM + kg + lc * 4);
      rw1 = *(const float4*)(W + (size_t)(lr + 32) * DIM + kg + lc * 4);
    }

    __syncthreads();  // buf[cur] fully written by all waves

#pragma unroll
    for (int k = 0; k < KC; ++k) {
      const float4 xv = *(const float4*)&xT[cur][k][tg * 4];
      const float4 w0 = *(const float4*)&wT[cur][k][eg * 8];
      const float4 w1 = *(const float4*)&wT[cur][k][eg * 8 + 4];
      const float xa[4] = {xv.x, xv.y, xv.z, xv.w};
      const float wa[8] = {w0.x, w0.y, w0.z, w0.w, w1.x, w1.y, w1.z, w1.w};
#pragma unroll
      for (int i = 0; i < 4; ++i)
#pragma unroll
        for (int j = 0; j < 8; ++j)
          acc[i][j] = fmaf(xa[i], wa[j], acc[i][j]);
    }

    // write next tile into the other buffer (vmcnt drain happens here, post-compute)
    if (more) {
      xT[nxt][lc * 4 + 0][lr +  0] = rx0.x; xT[nxt][lc * 4 + 1][lr +  0] = rx0.y;
      xT[nxt][lc * 4 + 2][lr +  0] = rx0.z; xT[nxt][lc * 4 + 3][lr +  0] = rx0.w;
      xT[nxt][lc * 4 + 0][lr + 32] = rx1.x; xT[nxt][lc * 4 + 1][lr + 32] = rx1.y;
      xT[nxt][lc * 4 + 2][lr + 32] = rx1.z; xT[nxt][lc * 4 + 3][lr + 32] = rx1.w;
      xT[nxt][lc * 4 + 0][lr + 64] = rx2.x; xT[nxt][lc * 4 + 1][lr + 64] = rx2.y;
      xT[nxt][lc * 4 + 2][lr + 64] = rx2.z; xT[nxt][lc * 4 + 3][lr + 64] = rx2.w;
      xT[nxt][lc * 4 + 0][lr + 96] = rx3.x; xT[nxt][lc * 4 + 1][lr + 96] = rx3.y;
      xT[nxt][lc * 4 + 2][lr + 96] = rx3.z; xT[nxt][lc * 4 + 3][lr + 96] = rx3.w;
      wT[nxt][lc * 4 + 0][lr +  0] = rw0.x; wT[nxt][lc * 4 + 1][lr +  0] = rw0.y;
      wT[nxt][lc * 4 + 2][lr +  0] = rw0.z; wT[nxt][lc * 4 + 3][lr +  0] = rw0.w;
      wT[nxt][lc * 4 + 0][lr + 32] = rw1.x; wT[nxt][lc * 4 + 1][lr + 32] = rw1.y;
      wT[nxt][lc * 4 + 2][lr + 32] = rw1.z; wT[nxt][lc * 4 + 3][lr + 32] = rw1.w;
    }
  }

  float* outp = partials + (size_t)split * N_TOK * NE;
#pragma unroll
  for (int i = 0; i < 4; ++i) {
    const int t = t_base + tg * 4 + i;
    const float4 v0 = make_float4(acc[i][0], acc[i][1], acc[i][2], acc[i][3]);
    const float4 v1 = make_float4(acc[i][4], acc[i][5], acc[i][6], acc[i][7]);
    *(float4*)(outp + (size_t)t * NE + eg * 8)     = v0;
    *(float4*)(outp + (size_t)t * NE + eg * 8 + 4) = v1;
  }
}

__global__ __launch_bounds__(256) void route_kernel(
    const float* __restrict__ partials, int ks,
    float* __restrict__ out, int* __restrict__ ws_idx,
    float* __restrict__ ws_probs, int* __restrict__ counts) {
  __shared__ int cnt[NE];
  const int tid = threadIdx.x;
  if (tid < NE) cnt[tid] = 0;
  __syncthreads();
  const int t = blockIdx.x * 256 + tid;

  // top-2 with jax.lax.top_k tie semantics (lower index wins on equality)
  float b1 = -INFINITY, b2 = -INFINITY;
  int i1 = 0, i2 = 0;
  for (int e = 0; e < NE; e += 4) {
    float4 s = *(const float4*)(partials + (size_t)t * NE + e);
    for (int sp = 1; sp < ks; ++sp) {
      const float4 v = *(const float4*)(partials + (size_t)sp * N_TOK * NE + (size_t)t * NE + e);
      s.x += v.x; s.y += v.y; s.z += v.z; s.w += v.w;
    }
    const float vv[4] = {s.x, s.y, s.z, s.w};
#pragma unroll
    for (int j = 0; j < 4; ++j) {
      const float v = vv[j];
      const int idx = e + j;
      if (v > b1)      { b2 = b1; i2 = i1; b1 = v; i1 = idx; }
      else if (v > b2) { b2 = v; i2 = idx; }
    }
  }
  // softmax over the two kept scores (max-subtracted, like jax.nn.softmax)
  const float ed = expf(b2 - b1);
  const float p1 = 1.0f / (1.0f + ed);
  const float p2 = ed / (1.0f + ed);

  out[(size_t)t * 2]     = p1;
  out[(size_t)t * 2 + 1] = p2;
  out[(size_t)N_TOK * 2 + t * 2]     = (float)i1;  // indices stored as f32
  out[(size_t)N_TOK * 2 + t * 2 + 1] = (float)i2;
  ws_idx[t * 2] = i1;  ws_idx[t * 2 + 1] = i2;
  ws_probs[t * 2] = p1; ws_probs[t * 2 + 1] = p2;

  atomicAdd(&cnt[i1], 1);
  atomicAdd(&cnt[i2], 1);
  __syncthreads();
  if (tid < NE) atomicAdd(&counts[tid], cnt[tid]);
}

__global__ __launch_bounds__(256) void capacity_kernel(
    const int* __restrict__ counts, const int* __restrict__ ws_idx,
    const float* __restrict__ ws_probs, float* __restrict__ out) {
  const int e = blockIdx.x;
  const int cnt = counts[e];
  if (threadIdx.x == 0) out[(size_t)N_TOK * 4 + e] = (float)cnt;
  if (cnt <= CAP) return;  // cold path below: essentially never taken for this input
  for (int i = threadIdx.x; i < N_TOK * 2; i += 256) {
    if (ws_idx[i] != e) continue;
    const float p = ws_probs[i];
    const int tok = i >> 1;
    int rank = 0;
    for (int j = 0; j < N_TOK * 2; ++j) {
      if (ws_idx[j] != e) continue;
      const float q = ws_probs[j];
      if (q > p || (q == p && (j >> 1) < tok)) ++rank;
    }
    if (rank >= CAP) {
      out[i] = 0.0f;                                   // dropped prob
      out[(size_t)N_TOK * 2 + i] = 2147483648.0f;      // INT32_MAX as f32
    }
  }
}

extern "C" void kernel_launch(void* const* d_in, const int* in_sizes, int n_in,
                              void* d_out, int out_size, void* d_ws, size_t ws_size,
                              hipStream_t stream) {
  const float* x = (const float*)d_in[0];
  const float* W = (const float*)d_in[1];
  float* out = (float*)d_out;

  char* ws = (char*)d_ws;
  int*   counts   = (int*)ws;
  int*   ws_idx   = (int*)(ws + 256);
  float* ws_probs = (float*)(ws + 256 + (size_t)N_TOK * 2 * 4);
  float* partials = (float*)(ws + 262400);

  const size_t base = 262400;
  const size_t per  = (size_t)N_TOK * NE * 4;  // 4 MB per K-split partial
  int ks = 1;
  if (ws_size >= base + 8 * per)      ks = 8;   // 1024 blocks: 3 resident blocks/CU (LDS-capped)
  else if (ws_size >= base + 4 * per) ks = 4;
  else if (ws_size >= base + 2 * per) ks = 2;

  hipMemsetAsync(counts, 0, NE * sizeof(int), stream);
  gemm_logits_kernel<<<NTILES * ks, 256, 0, stream>>>(x, W, partials, ks);
  route_kernel<<<N_TOK / 256, 256, 0, stream>>>(partials, ks, out, ws_idx, ws_probs, counts);
  capacity_kernel<<<NE, 256, 0, stream>>>(counts, ws_idx, ws_probs, out);
}

// Round 2
// 443.139 us; speedup vs baseline: 1.0640x; 1.0640x over previous
//
#include <hip/hip_runtime.h>
#include <math.h>

#define N_TOK  16384
#define DIM    4096
#define NE     64
#define CAP    640
#define KC     32
#define TM     128
#define NTILES (N_TOK / TM)   // 128

// ws layout:
// [0,256):                     counts (64 int, zeroed per call)
// [256, 256+128K):             ws_idx   (int,   N*2)
// [256+128K, 256+256K):        ws_probs (float, N*2)
// [262400, ...):               partials (ks * N * 64 floats)

__device__ __forceinline__ void gl_lds16(const float* g, float* l) {
  // async global->LDS, 16B per lane; LDS dest must be wave-uniform base + lane*16
  __builtin_amdgcn_global_load_lds((const __attribute__((address_space(1))) void*)g,
                                   (__attribute__((address_space(3))) void*)l, 16, 0, 0);
}

// LDS layout (per buffer):
//   xs: [t][c] row-major, 32 floats per row, NO padding (gload_lds needs linear).
//       slot (t, c) holds global x[t_base+t][kg + (c ^ 4*((t>>2)&7))]  (XOR on source)
//   ws: [e][c] row-major, slot (e,c) holds W[e][kg + (c ^ 4*((e>>3)&7))]
// Reads use the same XOR -> bank quad = 4*(kq^key), distinct across the 8 broadcast
// groups of a wave -> conflict-free ds_read_b128.
__global__ __launch_bounds__(256, 3) void gemm_logits_kernel(
    const float* __restrict__ x, const float* __restrict__ W,
    float* __restrict__ partials, int ks) {
  const int tile  = blockIdx.x % NTILES;
  const int split = blockIdx.x / NTILES;
  const int klen  = DIM / ks;
  const int k0    = split * klen;
  const int t_base = tile * TM;

  __shared__ float xs[2][KC * TM];  // 2 x 16 KB
  __shared__ float wss[2][KC * NE]; // 2 x  8 KB   (total 48 KB -> 3 blocks/CU)

  const int tid = threadIdx.x;
  const int tg  = tid >> 3;   // 0..31
  const int eg  = tid & 7;    // 0..7
  const int lk  = tid & 7;    // float4 slot within a 32-float row

  // swizzle keys for the staged global source addresses (involution with read side)
  const int klx  = 4 * (lk ^ ((tg >> 2) & 7));
  const int klw0 = 4 * (lk ^ (tg >> 3));        // rows 0..31  -> key e>>3 in 0..3
  const int klw1 = 4 * (lk ^ ((tg >> 3) + 4));  // rows 32..63 -> key 4..7

  const float* xg  = x + (size_t)(t_base + tg) * DIM + k0 + klx;
  const float* wg0 = W + (size_t)tg * DIM + k0 + klw0;
  const float* wg1 = W + (size_t)(tg + 32) * DIM + k0 + klw1;
  float* xl = &xs[0][0]  + tid * 4;   // + buf*4096 + v*1024
  float* wl = &wss[0][0] + tid * 4;   // + buf*2048 + v*1024

  float acc[4][8];
#pragma unroll
  for (int i = 0; i < 4; ++i)
#pragma unroll
    for (int j = 0; j < 8; ++j) acc[i][j] = 0.f;

  const int niter = klen / KC;

  // prologue: stage tile 0 into buf 0
  {
    gl_lds16(xg,            xl);
    gl_lds16(xg + 32 * DIM, xl + 1024);
    gl_lds16(xg + 64 * DIM, xl + 2048);
    gl_lds16(xg + 96 * DIM, xl + 3072);
    gl_lds16(wg0, wl);
    gl_lds16(wg1, wl + 1024);
  }
  __syncthreads();  // drains vmcnt: buf0 ready

  const int twz = tg & 7;
  for (int it = 0; it < niter; ++it) {
    const int cur = it & 1;
    const int nxt = cur ^ 1;

    // issue next tile's async loads EARLY; they fly under the FMAs below
    if (it + 1 < niter) {
      const int ko = (it + 1) * KC;
      gl_lds16(xg + ko,            xl + nxt * 4096);
      gl_lds16(xg + ko + 32 * DIM, xl + nxt * 4096 + 1024);
      gl_lds16(xg + ko + 64 * DIM, xl + nxt * 4096 + 2048);
      gl_lds16(xg + ko + 96 * DIM, xl + nxt * 4096 + 3072);
      gl_lds16(wg0 + ko, wl + nxt * 2048);
      gl_lds16(wg1 + ko, wl + nxt * 2048 + 1024);
    }

    const float* xb = &xs[cur][0];
    const float* wb = &wss[cur][0];
#pragma unroll
    for (int kq = 0; kq < 8; ++kq) {
      const int xo = 4 * (kq ^ twz);
      const int wo = 4 * (kq ^ eg);
      float xa[16];
#pragma unroll
      for (int i = 0; i < 4; ++i) {
        const float4 v = *(const float4*)(xb + (4 * tg + i) * 32 + xo);
        xa[i * 4 + 0] = v.x; xa[i * 4 + 1] = v.y; xa[i * 4 + 2] = v.z; xa[i * 4 + 3] = v.w;
      }
      float wa[32];
#pragma unroll
      for (int j = 0; j < 8; ++j) {
        const float4 v = *(const float4*)(wb + (8 * eg + j) * 32 + wo);
        wa[j * 4 + 0] = v.x; wa[j * 4 + 1] = v.y; wa[j * 4 + 2] = v.z; wa[j * 4 + 3] = v.w;
      }
#pragma unroll
      for (int i = 0; i < 4; ++i)
#pragma unroll
        for (int j = 0; j < 8; ++j) {
          acc[i][j] = fmaf(xa[i * 4 + 0], wa[j * 4 + 0], acc[i][j]);
          acc[i][j] = fmaf(xa[i * 4 + 1], wa[j * 4 + 1], acc[i][j]);
          acc[i][j] = fmaf(xa[i * 4 + 2], wa[j * 4 + 2], acc[i][j]);
          acc[i][j] = fmaf(xa[i * 4 + 3], wa[j * 4 + 3], acc[i][j]);
        }
    }

    __syncthreads();  // all waves done reading buf[cur]; buf[nxt] loads drained
  }

  float* outp = partials + (size_t)split * N_TOK * NE;
#pragma unroll
  for (int i = 0; i < 4; ++i) {
    const int t = t_base + tg * 4 + i;
    const float4 v0 = make_float4(acc[i][0], acc[i][1], acc[i][2], acc[i][3]);
    const float4 v1 = make_float4(acc[i][4], acc[i][5], acc[i][6], acc[i][7]);
    *(float4*)(outp + (size_t)t * NE + eg * 8)     = v0;
    *(float4*)(outp + (size_t)t * NE + eg * 8 + 4) = v1;
  }
}

__global__ __launch_bounds__(64) void route_kernel(
    const float* __restrict__ partials, int ks,
    float* __restrict__ out, int* __restrict__ ws_idx,
    float* __restrict__ ws_probs, int* __restrict__ counts) {
  __shared__ int cnt[NE];
  const int tid = threadIdx.x;
  cnt[tid] = 0;  // blockDim == NE == 64
  __syncthreads();
  const int t = blockIdx.x * 64 + tid;

  // split-OUTER accumulation: per split the wave sweeps a dense 16 KB region
  // (64 tokens x 256B) -> L1-resident, no thrash across splits.
  float4 s[16];
  {
    const float* p = partials + (size_t)t * NE;
#pragma unroll
    for (int c = 0; c < 16; ++c) s[c] = *(const float4*)(p + 4 * c);
  }
  for (int sp = 1; sp < ks; ++sp) {
    const float* p = partials + (size_t)sp * N_TOK * NE + (size_t)t * NE;
#pragma unroll
    for (int c = 0; c < 16; ++c) {
      const float4 v = *(const float4*)(p + 4 * c);
      s[c].x += v.x; s[c].y += v.y; s[c].z += v.z; s[c].w += v.w;
    }
  }

  // top-2 with jax.lax.top_k tie semantics (lower index wins on equality)
  float b1 = -INFINITY, b2 = -INFINITY;
  int i1 = 0, i2 = 0;
#pragma unroll
  for (int c = 0; c < 16; ++c) {
    const float vv[4] = {s[c].x, s[c].y, s[c].z, s[c].w};
#pragma unroll
    for (int j = 0; j < 4; ++j) {
      const float v = vv[j];
      const int idx = c * 4 + j;
      if (v > b1)      { b2 = b1; i2 = i1; b1 = v; i1 = idx; }
      else if (v > b2) { b2 = v; i2 = idx; }
    }
  }
  const float ed = expf(b2 - b1);
  const float p1 = 1.0f / (1.0f + ed);
  const float p2 = ed / (1.0f + ed);

  out[(size_t)t * 2]     = p1;
  out[(size_t)t * 2 + 1] = p2;
  out[(size_t)N_TOK * 2 + t * 2]     = (float)i1;  // indices stored as f32
  out[(size_t)N_TOK * 2 + t * 2 + 1] = (float)i2;
  ws_idx[t * 2] = i1;  ws_idx[t * 2 + 1] = i2;
  ws_probs[t * 2] = p1; ws_probs[t * 2 + 1] = p2;

  atomicAdd(&cnt[i1], 1);
  atomicAdd(&cnt[i2], 1);
  __syncthreads();
  atomicAdd(&counts[tid], cnt[tid]);
}

__global__ __launch_bounds__(256) void capacity_kernel(
    const int* __restrict__ counts, const int* __restrict__ ws_idx,
    const float* __restrict__ ws_probs, float* __restrict__ out) {
  const int e = blockIdx.x;
  const int cnt = counts[e];
  if (threadIdx.x == 0) out[(size_t)N_TOK * 4 + e] = (float)cnt;
  if (cnt <= CAP) return;  // cold path: essentially never taken for this input
  for (int i = threadIdx.x; i < N_TOK * 2; i += 256) {
    if (ws_idx[i] != e) continue;
    const float p = ws_probs[i];
    const int tok = i >> 1;
    int rank = 0;
    for (int j = 0; j < N_TOK * 2; ++j) {
      if (ws_idx[j] != e) continue;
      const float q = ws_probs[j];
      if (q > p || (q == p && (j >> 1) < tok)) ++rank;
    }
    if (rank >= CAP) {
      out[i] = 0.0f;                                   // dropped prob
      out[(size_t)N_TOK * 2 + i] = 2147483648.0f;      // INT32_MAX as f32
    }
  }
}

extern "C" void kernel_launch(void* const* d_in, const int* in_sizes, int n_in,
                              void* d_out, int out_size, void* d_ws, size_t ws_size,
                              hipStream_t stream) {
  const float* x = (const float*)d_in[0];
  const float* W = (const float*)d_in[1];
  float* out = (float*)d_out;

  char* ws = (char*)d_ws;
  int*   counts   = (int*)ws;
  int*   ws_idx   = (int*)(ws + 256);
  float* ws_probs = (float*)(ws + 256 + (size_t)N_TOK * 2 * 4);
  float* partials = (float*)(ws + 262400);

  const size_t base = 262400;
  const size_t per  = (size_t)N_TOK * NE * 4;  // 4 MB per K-split partial
  int ks = 1;
  if (ws_size >= base + 8 * per)      ks = 8;   // 1024 blocks: 3 resident/CU (48 KB LDS)
  else if (ws_size >= base + 4 * per) ks = 4;
  else if (ws_size >= base + 2 * per) ks = 2;

  hipMemsetAsync(counts, 0, NE * sizeof(int), stream);
  gemm_logits_kernel<<<NTILES * ks, 256, 0, stream>>>(x, W, partials, ks);
  route_kernel<<<N_TOK / 64, 64, 0, stream>>>(partials, ks, out, ws_idx, ws_probs, counts);
  capacity_kernel<<<NE, 256, 0, stream>>>(counts, ws_idx, ws_probs, out);
}